// Round 6
// baseline (455.139 us; speedup 1.0000x reference)
//
#include <hip/hip_runtime.h>
#include <math.h>

#define NU   16384
#define NI   4096
#define DDIM 64
#define BB   2048
#define GSTR8 2056   // u8 g-tile stride: 4-row (hi-group) offset = 2056*4 B = 8 banks apart

typedef unsigned short u16;
typedef unsigned char  u8;
typedef __attribute__((ext_vector_type(8))) short short8;
typedef __attribute__((ext_vector_type(4))) float f32x4;

// fp32 -> bf16 RNE (for embeddings feeding MFMA)
static __device__ __forceinline__ u16 f2bf(float f) {
    union { float f; unsigned int u; } v; v.f = f;
    unsigned int u = v.u + 0x7FFFu + ((v.u >> 16) & 1u);
    return (u16)(u >> 16);
}

// rating [1,5] -> u8 [1,201], 0 = NaN sentinel; decode err <= 0.01
static __device__ __forceinline__ u8 enc_r(float r) {
    return (r == r) ? (u8)(__float2int_rn((r - 1.0f) * 50.0f) + 1) : (u8)0;
}

// ===== k_qprep: Ubf[b][k]=bf16(E[uidx[b]][k]); qinfo[b]={ub, 1/|u|} =====
__global__ __launch_bounds__(256) void k_qprep(
    const float* __restrict__ E, const int* __restrict__ uidx,
    u16* __restrict__ Ubf, int2* __restrict__ qinfo)
{
    const int lane = threadIdx.x & 63;
    const int b = blockIdx.x * 4 + (threadIdx.x >> 6);
    const int ub = uidx[b];
    const float e = E[(size_t)ub * DDIM + lane];
    float ss = e * e;
#pragma unroll
    for (int o = 32; o > 0; o >>= 1) ss += __shfl_xor(ss, o);
    Ubf[b * DDIM + lane] = f2bf(e);
    if (lane == 0) qinfo[b] = make_int2(ub, __float_as_int(rsqrtf(ss)));
}

// ===== k_fused: block = 16-row n-tile.
// Phase A: stream R rows (register-prefetched, ping-pong row buffer, ONE barrier
//          per row), stats in regs, item-gather -> u8 LDS g tile.
// Phase B: 2x MFMA 16x16x32 bf16 per b-tile vs all 2048 b, epilogue from LDS,
//          per-block partials (no atomics). Exports avgAll[n].
// LDS ~45.4 KB -> 3 blocks/CU. =====
__global__ __launch_bounds__(256) void k_fused(
    const float* __restrict__ R, const float* __restrict__ E,
    const int* __restrict__ iidx, const u16* __restrict__ Ubf,
    const int2* __restrict__ qinfo, float2* __restrict__ partials,
    float* __restrict__ avgAll)
{
    __shared__ u16 s_ii[BB];           // 4 KB
    __shared__ u8  rowq[2][NI];        // 8 KB ping-pong
    __shared__ u8  g[16][GSTR8];       // 32.9 KB
    __shared__ float sAvg[16], sInv[16];
    __shared__ float redS[2][4], redC[2][4];

    const int tid  = threadIdx.x;
    const int lane = tid & 63;
    const int wid  = tid >> 6;
    const int n0   = blockIdx.x * 16;

    for (int t = tid; t < BB; t += 256) s_ii[t] = (u16)iidx[t];

    // embedding inv-norms: wave wid -> rows wid*4..+3
#pragma unroll
    for (int rs = 0; rs < 4; ++rs) {
        const int n = n0 + wid * 4 + rs;
        const float e = E[(size_t)n * DDIM + lane];
        float ss = e * e;
#pragma unroll
        for (int o = 32; o > 0; o >>= 1) ss += __shfl_xor(ss, o);
        if (lane == 0) sInv[wid * 4 + rs] = rsqrtf(ss);
    }

    // ---- Phase A (register-prefetched pipeline) ----
    float4 vv[4];
    {
        const float4* R4 = (const float4*)(R + (size_t)n0 * NI);
#pragma unroll
        for (int j = 0; j < 4; ++j) vv[j] = R4[tid + j * 256];
    }

#pragma unroll 1
    for (int rr = 0; rr < 16; ++rr) {
        const int p = rr & 1;

        // issue prefetch of next row (clamped; row 15 re-read is an L2 hit)
        float4 vn[4];
        {
            const int np = n0 + ((rr < 15) ? rr + 1 : 15);
            const float4* Rn = (const float4*)(R + (size_t)np * NI);
#pragma unroll
            for (int j = 0; j < 4; ++j) vn[j] = Rn[tid + j * 256];
        }

        // process current row: stats + u8 encode -> rowq[p]
        float sum = 0.f, cnt = 0.f;
#pragma unroll
        for (int j = 0; j < 4; ++j) {
            const float4 v = vv[j];
            if (v.x == v.x) { sum += v.x; cnt += 1.f; }
            if (v.y == v.y) { sum += v.y; cnt += 1.f; }
            if (v.z == v.z) { sum += v.z; cnt += 1.f; }
            if (v.w == v.w) { sum += v.w; cnt += 1.f; }
            uchar4 q;
            q.x = enc_r(v.x); q.y = enc_r(v.y); q.z = enc_r(v.z); q.w = enc_r(v.w);
            *(uchar4*)&rowq[p][(tid + j * 256) * 4] = q;
        }
#pragma unroll
        for (int o = 32; o > 0; o >>= 1) {
            sum += __shfl_xor(sum, o);
            cnt += __shfl_xor(cnt, o);
        }
        if (lane == 0) { redS[p][wid] = sum; redC[p][wid] = cnt; }

        __syncthreads();   // rowq[p] + reds ready; also protects rowq[p^1] WAR

        if (tid == 0) {
            const float S = redS[p][0] + redS[p][1] + redS[p][2] + redS[p][3];
            const float C = redC[p][0] + redC[p][1] + redC[p][2] + redC[p][3];
            const float a = (C > 0.f) ? (S / C) : 0.f;
            sAvg[rr] = a;
            avgAll[n0 + rr] = a;
        }
        // packed gather: each thread produces 2 dwords of g[rr]
#pragma unroll
        for (int t = 0; t < 2; ++t) {
            const int b4 = (tid + t * 256) * 4;
            const ushort4 ii = *(const ushort4*)&s_ii[b4];
            uchar4 q;
            q.x = rowq[p][ii.x]; q.y = rowq[p][ii.y];
            q.z = rowq[p][ii.z]; q.w = rowq[p][ii.w];
            *(uchar4*)&g[rr][b4] = q;
        }
        // rotate prefetch
#pragma unroll
        for (int j = 0; j < 4; ++j) vv[j] = vn[j];
    }
    __syncthreads();       // all g + sAvg + sInv ready

    // ---- Phase B ----
    const int lo = lane & 15;
    const int hi = lane >> 4;

    short8 a[2];
#pragma unroll
    for (int kg = 0; kg < 2; ++kg) {
        const float* ep = E + (size_t)(n0 + lo) * DDIM + kg * 32 + hi * 8;
        const float4 e0 = *(const float4*)(ep);
        const float4 e1 = *(const float4*)(ep + 4);
        union { short8 v; u16 u[8]; } t;
        t.u[0] = f2bf(e0.x); t.u[1] = f2bf(e0.y); t.u[2] = f2bf(e0.z); t.u[3] = f2bf(e0.w);
        t.u[4] = f2bf(e1.x); t.u[5] = f2bf(e1.y); t.u[6] = f2bf(e1.z); t.u[7] = f2bf(e1.w);
        a[kg] = t.v;
    }
    float avr[4], ivr[4];
#pragma unroll
    for (int r = 0; r < 4; ++r) { avr[r] = sAvg[hi * 4 + r]; ivr[r] = sInv[hi * 4 + r]; }

    float2* pout = partials + (size_t)blockIdx.x * BB;

#pragma unroll 1
    for (int j = 0; j < 32; ++j) {
        const int b0 = (j * 4 + wid) * 16;
        const int2 q = qinfo[b0 + lo];
        const float inv_mu = __int_as_float(q.y);

        const short8 bf0 = *(const short8*)(Ubf + (size_t)(b0 + lo) * DDIM + hi * 8);
        const short8 bf1 = *(const short8*)(Ubf + (size_t)(b0 + lo) * DDIM + 32 + hi * 8);

        f32x4 c = {0.f, 0.f, 0.f, 0.f};
        c = __builtin_amdgcn_mfma_f32_16x16x32_bf16(a[0], bf0, c, 0, 0, 0);
        c = __builtin_amdgcn_mfma_f32_16x16x32_bf16(a[1], bf1, c, 0, 0, 0);

        float fnum = 0.f, fden = 0.f;
#pragma unroll
        for (int r = 0; r < 4; ++r) {
            const int nr = n0 + hi * 4 + r;                  // C/D row (m89 mapping)
            const u8 qg = g[hi * 4 + r][b0 + lo];
            const bool valid = (qg != 0) && (nr != q.x);
            const float gv = (float)(int)qg * 0.02f + 0.98f; // (qg-1)*0.02 + 1
            const float s  = valid ? c[r] * (inv_mu * ivr[r]) : 0.f;
            fnum += (gv - avr[r]) * s;                       // s==0 kills invalid
            fden += fabsf(s);
        }
        fnum += __shfl_xor(fnum, 16); fden += __shfl_xor(fden, 16);
        fnum += __shfl_xor(fnum, 32); fden += __shfl_xor(fden, 32);
        if (lane < 16) pout[b0 + lane] = make_float2(fnum, fden);
    }
}

// ===== k_final: reduce partials, finalize =====
__global__ __launch_bounds__(256) void k_final(
    const float2* __restrict__ partials, const int2* __restrict__ qinfo,
    const float* __restrict__ avgAll, float* __restrict__ out)
{
    __shared__ float sn[8][32], sd[8][32];
    const int tid = threadIdx.x;
    const int bl  = tid & 31;
    const int ch  = tid >> 5;
    const int b   = blockIdx.x * 32 + bl;
    float n = 0.f, d = 0.f;
    for (int blk = ch; blk < NU / 16; blk += 8) {
        const float2 p = partials[(size_t)blk * BB + b];
        n += p.x; d += p.y;
    }
    sn[ch][bl] = n; sd[ch][bl] = d;
    __syncthreads();
    if (tid < 32) {
        float N = 0.f, D = 0.f;
#pragma unroll
        for (int c2 = 0; c2 < 8; ++c2) { N += sn[c2][tid]; D += sd[c2][tid]; }
        const int bb = blockIdx.x * 32 + tid;
        const float au = avgAll[qinfo[bb].x];
        out[bb] = (D == 0.f) ? au : (au + N / D);
    }
}

// ===== Launch =====
extern "C" void kernel_launch(void* const* d_in, const int* in_sizes, int n_in,
                              void* d_out, int out_size, void* d_ws, size_t ws_size,
                              hipStream_t stream)
{
    const float* R    = (const float*)d_in[0];
    const float* E    = (const float*)d_in[1];
    const int*   uidx = (const int*)d_in[2];
    const int*   iidx = (const int*)d_in[3];
    float* out = (float*)d_out;

    // ws carve: partials 16MiB | Ubf 256KB | qinfo 16KB | avgAll 64KB
    char* p = (char*)d_ws;
    float2* parts  = (float2*)p;  p += (size_t)(NU / 16) * BB * 8;
    u16*    Ubf    = (u16*)p;     p += (size_t)BB * DDIM * 2;
    int2*   qinfo  = (int2*)p;    p += (size_t)BB * 8;
    float*  avgAll = (float*)p;   p += (size_t)NU * 4;

    k_qprep<<<BB / 4, 256, 0, stream>>>(E, uidx, Ubf, qinfo);
    k_fused<<<NU / 16, 256, 0, stream>>>(R, E, iidx, Ubf, qinfo, parts, avgAll);
    k_final<<<BB / 32, 256, 0, stream>>>(parts, qinfo, avgAll, out);
}